// Round 6
// baseline (39.168 us; speedup 1.0000x reference)
//
#include <hip/hip_runtime.h>
#include <math.h>

// out = [h0, h1, atan2(softsign(h2), softsign(h3))]
// h = W @ [x0, x1, x2, sin(x2), cos(x2), 1] + b
//
// LDS-staged transpose (R4) + non-temporal output stores (R6):
// output is write-once/never-re-read -> stream it past L2/L3 so the 100 MB
// input stays fully Infinity-Cache-resident across graph replays.
// (__builtin_nontemporal_store needs a native vector type, not HIP float4.)
//
// softsign fold: atan2(y/(1+|y|), x/(1+|x|)) == atan2(y*(1+|x|), x*(1+|y|)).

typedef float nat_f4 __attribute__((ext_vector_type(4)));

__device__ __forceinline__ float fast_atan2f(float y, float x) {
    const float ax = fabsf(x), ay = fabsf(y);
    const float mx = fmaxf(ax, ay), mn = fminf(ax, ay);
    float r = mn * __builtin_amdgcn_rcpf(mx);      // mn/mx in [0,1]; NaN if mx==0 (fixed below)
    const float t = r * r;
    // minimax atan(r) on [0,1], |err| ~ 1e-4 rad
    float p = fmaf(t, -0.0851330f, 0.1801410f);
    p = fmaf(t, p, -0.3302995f);
    p = fmaf(t, p, 0.9998660f);
    float a = r * p;
    a = (ay > ax)   ? (1.57079632679f - a) : a;    // first-octant fold
    a = (x < 0.0f)  ? (3.14159265359f - a) : a;    // left half-plane
    a = copysignf(a, y);                            // sign of y
    a = (mx == 0.0f) ? 0.0f : a;                    // atan2(0,0) = 0, kill NaN
    return a;
}

__global__ __launch_bounds__(256, 8) void net_main_kernel(
    const float4* __restrict__ x4,
    const float*  __restrict__ W,
    const float*  __restrict__ bias,
    float4*       __restrict__ o4,
    int nf4)    // total float4 count = nquad*3
{
    __shared__ float4 sbuf[768];   // 12 KB: 256 threads x 4 rows x 3 floats

    const int tid  = threadIdx.x;
    const int base = blockIdx.x * 768;

    // Uniform -> scalar loads; fold ones-column into bias.
    float w[4][5];
    float wb[4];
#pragma unroll
    for (int r = 0; r < 4; ++r) {
#pragma unroll
        for (int c = 0; c < 5; ++c) w[r][c] = W[r * 6 + c];
        wb[r] = W[r * 6 + 5] + bias[r];
    }

    // Phase 1: perfectly coalesced global -> LDS.
#pragma unroll
    for (int k = 0; k < 3; ++k) {
        const int idx = k * 256 + tid;
        if (base + idx < nf4) sbuf[idx] = x4[base + idx];
    }
    __syncthreads();

    // Phase 2: strided (48B) row reads from LDS, compute, rewrite in place.
    // Thread tid owns slots [3*tid, 3*tid+2] exclusively -> no barrier needed
    // between its read and its rewrite.
    const float4 qa = sbuf[3 * tid + 0];
    const float4 qb = sbuf[3 * tid + 1];
    const float4 qc = sbuf[3 * tid + 2];

    const float rx[4][3] = {
        {qa.x, qa.y, qa.z},
        {qa.w, qb.x, qb.y},
        {qb.z, qb.w, qc.x},
        {qc.y, qc.z, qc.w},
    };

    float res[4][3];
#pragma unroll
    for (int i = 0; i < 4; ++i) {
        const float x0 = rx[i][0];
        const float x1 = rx[i][1];
        const float an = rx[i][2];
        const float s = __sinf(an);
        const float c = __cosf(an);

        float h[4];
#pragma unroll
        for (int r = 0; r < 4; ++r) {
            float acc = wb[r];
            acc = fmaf(c,  w[r][4], acc);
            acc = fmaf(s,  w[r][3], acc);
            acc = fmaf(an, w[r][2], acc);
            acc = fmaf(x1, w[r][1], acc);
            acc = fmaf(x0, w[r][0], acc);
            h[r] = acc;
        }

        res[i][0] = h[0];
        res[i][1] = h[1];
        res[i][2] = fast_atan2f(h[2] * (1.0f + fabsf(h[3])),
                                h[3] * (1.0f + fabsf(h[2])));
    }

    sbuf[3 * tid + 0] = make_float4(res[0][0], res[0][1], res[0][2], res[1][0]);
    sbuf[3 * tid + 1] = make_float4(res[1][1], res[1][2], res[2][0], res[2][1]);
    sbuf[3 * tid + 2] = make_float4(res[2][2], res[3][0], res[3][1], res[3][2]);
    __syncthreads();

    // Phase 3: perfectly coalesced LDS -> global, non-temporal (stream past L3).
    nat_f4* onat = reinterpret_cast<nat_f4*>(o4);
    const nat_f4* snat = reinterpret_cast<const nat_f4*>(sbuf);
#pragma unroll
    for (int k = 0; k < 3; ++k) {
        const int idx = k * 256 + tid;
        if (base + idx < nf4) {
            __builtin_nontemporal_store(snat[idx], &onat[base + idx]);
        }
    }
}

// Tail: rows not covered by the 4-row vector path (B % 4 != 0).
__global__ void net_tail_kernel(
    const float* __restrict__ x,
    const float* __restrict__ W,
    const float* __restrict__ bias,
    float*       __restrict__ out,
    int row0, int nrows)
{
    const int i = blockIdx.x * blockDim.x + threadIdx.x;
    if (i >= nrows) return;
    const int row = row0 + i;

    const float x0 = x[row * 3 + 0];
    const float x1 = x[row * 3 + 1];
    const float an = x[row * 3 + 2];
    const float s = __sinf(an);
    const float c = __cosf(an);

    float h[4];
#pragma unroll
    for (int r = 0; r < 4; ++r) {
        float acc = W[r * 6 + 5] + bias[r];
        acc = fmaf(c,  W[r * 6 + 4], acc);
        acc = fmaf(s,  W[r * 6 + 3], acc);
        acc = fmaf(an, W[r * 6 + 2], acc);
        acc = fmaf(x1, W[r * 6 + 1], acc);
        acc = fmaf(x0, W[r * 6 + 0], acc);
        h[r] = acc;
    }
    out[row * 3 + 0] = h[0];
    out[row * 3 + 1] = h[1];
    out[row * 3 + 2] = fast_atan2f(h[2] * (1.0f + fabsf(h[3])),
                                   h[3] * (1.0f + fabsf(h[2])));
}

extern "C" void kernel_launch(void* const* d_in, const int* in_sizes, int n_in,
                              void* d_out, int out_size, void* d_ws, size_t ws_size,
                              hipStream_t stream) {
    const float* x    = (const float*)d_in[0];
    const float* W    = (const float*)d_in[1];
    const float* bias = (const float*)d_in[2];
    float* out        = (float*)d_out;

    const int B = in_sizes[0] / 3;          // number of rows
    const int nquad = B / 4;                // 4-row groups
    const int tail_rows = B - nquad * 4;
    const int nf4 = nquad * 3;              // total float4s in vector path

    if (nquad > 0) {
        const int block = 256;
        const int grid = (nquad + block - 1) / block;   // 256 quads per block
        net_main_kernel<<<grid, block, 0, stream>>>(
            (const float4*)x, W, bias, (float4*)out, nf4);
    }
    if (tail_rows > 0) {
        net_tail_kernel<<<1, 64, 0, stream>>>(x, W, bias, out, nquad * 4, tail_rows);
    }
}

// Round 7
// 35.118 us; speedup vs baseline: 1.1153x; 1.1153x over previous
//
#include <hip/hip_runtime.h>
#include <math.h>

// out = [h0, h1, atan2(softsign(h2), softsign(h3))]
// h = W @ [x0, x1, x2, sin(x2), cos(x2), 1] + b
//
// R4 structure (LDS-staged transpose, plain coalesced stores — NT stores
// regressed 11% in R6, reverted) + R7: phase-1 staging via
// __builtin_amdgcn_global_load_lds (HBM -> LDS direct, no VGPR round trip).
// Our linear LDS layout is exactly the required wave-uniform-base + lane*16.
//
// softsign fold: atan2(y/(1+|y|), x/(1+|x|)) == atan2(y*(1+|x|), x*(1+|y|)).

typedef unsigned int u32;

__device__ __forceinline__ float fast_atan2f(float y, float x) {
    const float ax = fabsf(x), ay = fabsf(y);
    const float mx = fmaxf(ax, ay), mn = fminf(ax, ay);
    float r = mn * __builtin_amdgcn_rcpf(mx);      // mn/mx in [0,1]; NaN if mx==0 (fixed below)
    const float t = r * r;
    // minimax atan(r) on [0,1], |err| ~ 1e-4 rad
    float p = fmaf(t, -0.0851330f, 0.1801410f);
    p = fmaf(t, p, -0.3302995f);
    p = fmaf(t, p, 0.9998660f);
    float a = r * p;
    a = (ay > ax)   ? (1.57079632679f - a) : a;    // first-octant fold
    a = (x < 0.0f)  ? (3.14159265359f - a) : a;    // left half-plane
    a = copysignf(a, y);                            // sign of y
    a = (mx == 0.0f) ? 0.0f : a;                    // atan2(0,0) = 0, kill NaN
    return a;
}

__global__ __launch_bounds__(256, 8) void net_main_kernel(
    const float4* __restrict__ x4,
    const float*  __restrict__ W,
    const float*  __restrict__ bias,
    float4*       __restrict__ o4,
    int nf4)    // total float4 count = nquad*3
{
    __shared__ float4 sbuf[768];   // 12 KB: 256 threads x 4 rows x 3 floats

    const int tid  = threadIdx.x;
    const int base = blockIdx.x * 768;

    // Uniform -> scalar loads; fold ones-column into bias.
    float w[4][5];
    float wb[4];
#pragma unroll
    for (int r = 0; r < 4; ++r) {
#pragma unroll
        for (int c = 0; c < 5; ++c) w[r][c] = W[r * 6 + c];
        wb[r] = W[r * 6 + 5] + bias[r];
    }

    // Phase 1: coalesced global -> LDS, direct DMA (no VGPR round trip).
    if (base + 768 <= nf4) {
        const int wbase = tid & ~63;   // 64 * wave_id (wave-uniform LDS base)
#pragma unroll
        for (int k = 0; k < 3; ++k) {
            const int idx = k * 256 + tid;
            const u32 __attribute__((address_space(1)))* gp =
                (const u32 __attribute__((address_space(1)))*)(&x4[base + idx]);
            u32 __attribute__((address_space(3)))* lp =
                (u32 __attribute__((address_space(3)))*)(&sbuf[k * 256 + wbase]);
            __builtin_amdgcn_global_load_lds(gp, lp, 16, 0, 0);
        }
    } else {
#pragma unroll
        for (int k = 0; k < 3; ++k) {
            const int idx = k * 256 + tid;
            if (base + idx < nf4) sbuf[idx] = x4[base + idx];
        }
    }
    __syncthreads();

    // Phase 2: strided (48B) row reads from LDS, compute, rewrite in place.
    // Thread tid owns slots [3*tid, 3*tid+2] exclusively -> no barrier needed
    // between its read and its rewrite.
    const float4 qa = sbuf[3 * tid + 0];
    const float4 qb = sbuf[3 * tid + 1];
    const float4 qc = sbuf[3 * tid + 2];

    const float rx[4][3] = {
        {qa.x, qa.y, qa.z},
        {qa.w, qb.x, qb.y},
        {qb.z, qb.w, qc.x},
        {qc.y, qc.z, qc.w},
    };

    float res[4][3];
#pragma unroll
    for (int i = 0; i < 4; ++i) {
        const float x0 = rx[i][0];
        const float x1 = rx[i][1];
        const float an = rx[i][2];
        const float s = __sinf(an);
        const float c = __cosf(an);

        float h[4];
#pragma unroll
        for (int r = 0; r < 4; ++r) {
            float acc = wb[r];
            acc = fmaf(c,  w[r][4], acc);
            acc = fmaf(s,  w[r][3], acc);
            acc = fmaf(an, w[r][2], acc);
            acc = fmaf(x1, w[r][1], acc);
            acc = fmaf(x0, w[r][0], acc);
            h[r] = acc;
        }

        res[i][0] = h[0];
        res[i][1] = h[1];
        res[i][2] = fast_atan2f(h[2] * (1.0f + fabsf(h[3])),
                                h[3] * (1.0f + fabsf(h[2])));
    }

    sbuf[3 * tid + 0] = make_float4(res[0][0], res[0][1], res[0][2], res[1][0]);
    sbuf[3 * tid + 1] = make_float4(res[1][1], res[1][2], res[2][0], res[2][1]);
    sbuf[3 * tid + 2] = make_float4(res[2][2], res[3][0], res[3][1], res[3][2]);
    __syncthreads();

    // Phase 3: perfectly coalesced LDS -> global (plain stores).
#pragma unroll
    for (int k = 0; k < 3; ++k) {
        const int idx = k * 256 + tid;
        if (base + idx < nf4) o4[base + idx] = sbuf[idx];
    }
}

// Tail: rows not covered by the 4-row vector path (B % 4 != 0).
__global__ void net_tail_kernel(
    const float* __restrict__ x,
    const float* __restrict__ W,
    const float* __restrict__ bias,
    float*       __restrict__ out,
    int row0, int nrows)
{
    const int i = blockIdx.x * blockDim.x + threadIdx.x;
    if (i >= nrows) return;
    const int row = row0 + i;

    const float x0 = x[row * 3 + 0];
    const float x1 = x[row * 3 + 1];
    const float an = x[row * 3 + 2];
    const float s = __sinf(an);
    const float c = __cosf(an);

    float h[4];
#pragma unroll
    for (int r = 0; r < 4; ++r) {
        float acc = W[r * 6 + 5] + bias[r];
        acc = fmaf(c,  W[r * 6 + 4], acc);
        acc = fmaf(s,  W[r * 6 + 3], acc);
        acc = fmaf(an, W[r * 6 + 2], acc);
        acc = fmaf(x1, W[r * 6 + 1], acc);
        acc = fmaf(x0, W[r * 6 + 0], acc);
        h[r] = acc;
    }
    out[row * 3 + 0] = h[0];
    out[row * 3 + 1] = h[1];
    out[row * 3 + 2] = fast_atan2f(h[2] * (1.0f + fabsf(h[3])),
                                   h[3] * (1.0f + fabsf(h[2])));
}

extern "C" void kernel_launch(void* const* d_in, const int* in_sizes, int n_in,
                              void* d_out, int out_size, void* d_ws, size_t ws_size,
                              hipStream_t stream) {
    const float* x    = (const float*)d_in[0];
    const float* W    = (const float*)d_in[1];
    const float* bias = (const float*)d_in[2];
    float* out        = (float*)d_out;

    const int B = in_sizes[0] / 3;          // number of rows
    const int nquad = B / 4;                // 4-row groups
    const int tail_rows = B - nquad * 4;
    const int nf4 = nquad * 3;              // total float4s in vector path

    if (nquad > 0) {
        const int block = 256;
        const int grid = (nquad + block - 1) / block;   // 256 quads per block
        net_main_kernel<<<grid, block, 0, stream>>>(
            (const float4*)x, W, bias, (float4*)out, nf4);
    }
    if (tail_rows > 0) {
        net_tail_kernel<<<1, 64, 0, stream>>>(x, W, bias, out, nquad * 4, tail_rows);
    }
}

// Round 8
// 35.030 us; speedup vs baseline: 1.1181x; 1.0025x over previous
//
#include <hip/hip_runtime.h>
#include <math.h>

// out = [h0, h1, atan2(softsign(h2), softsign(h3))]
// h = W @ [x0, x1, x2, sin(x2), cos(x2), 1] + b
//
// R4 LDS-staged transpose + R7 global_load_lds DMA staging.
// R8: exact-path specialization — the benched shape divides evenly
// (nf4 % 768 == 0), so the hot kernel carries zero bounds checks.
// NT stores regressed 11% (R6) — plain stores. 91% of m13 copy ceiling.
//
// softsign fold: atan2(y/(1+|y|), x/(1+|x|)) == atan2(y*(1+|x|), x*(1+|y|)).

typedef unsigned int u32;

__device__ __forceinline__ float fast_atan2f(float y, float x) {
    const float ax = fabsf(x), ay = fabsf(y);
    const float mx = fmaxf(ax, ay), mn = fminf(ax, ay);
    float r = mn * __builtin_amdgcn_rcpf(mx);      // mn/mx in [0,1]; NaN if mx==0 (fixed below)
    const float t = r * r;
    // minimax atan(r) on [0,1], |err| ~ 1e-4 rad
    float p = fmaf(t, -0.0851330f, 0.1801410f);
    p = fmaf(t, p, -0.3302995f);
    p = fmaf(t, p, 0.9998660f);
    float a = r * p;
    a = (ay > ax)   ? (1.57079632679f - a) : a;    // first-octant fold
    a = (x < 0.0f)  ? (3.14159265359f - a) : a;    // left half-plane
    a = copysignf(a, y);                            // sign of y
    a = (mx == 0.0f) ? 0.0f : a;                    // atan2(0,0) = 0, kill NaN
    return a;
}

template <bool EXACT>
__global__ __launch_bounds__(256, 8) void net_main_kernel(
    const float4* __restrict__ x4,
    const float*  __restrict__ W,
    const float*  __restrict__ bias,
    float4*       __restrict__ o4,
    int nf4)    // total float4 count = nquad*3
{
    __shared__ float4 sbuf[768];   // 12 KB: 256 threads x 4 rows x 3 floats

    const int tid  = threadIdx.x;
    const int base = blockIdx.x * 768;

    // Uniform -> scalar loads; fold ones-column into bias.
    float w[4][5];
    float wb[4];
#pragma unroll
    for (int r = 0; r < 4; ++r) {
#pragma unroll
        for (int c = 0; c < 5; ++c) w[r][c] = W[r * 6 + c];
        wb[r] = W[r * 6 + 5] + bias[r];
    }

    // Phase 1: coalesced global -> LDS, direct DMA (no VGPR round trip).
    if (EXACT || base + 768 <= nf4) {
        const int wbase = tid & ~63;   // 64 * wave_id (wave-uniform LDS base)
#pragma unroll
        for (int k = 0; k < 3; ++k) {
            const int idx = k * 256 + tid;
            const u32 __attribute__((address_space(1)))* gp =
                (const u32 __attribute__((address_space(1)))*)(&x4[base + idx]);
            u32 __attribute__((address_space(3)))* lp =
                (u32 __attribute__((address_space(3)))*)(&sbuf[k * 256 + wbase]);
            __builtin_amdgcn_global_load_lds(gp, lp, 16, 0, 0);
        }
    } else {
#pragma unroll
        for (int k = 0; k < 3; ++k) {
            const int idx = k * 256 + tid;
            if (base + idx < nf4) sbuf[idx] = x4[base + idx];
        }
    }
    __syncthreads();

    // Phase 2: strided (48B) row reads from LDS, compute, rewrite in place.
    // Thread tid owns slots [3*tid, 3*tid+2] exclusively -> no barrier needed
    // between its read and its rewrite.
    const float4 qa = sbuf[3 * tid + 0];
    const float4 qb = sbuf[3 * tid + 1];
    const float4 qc = sbuf[3 * tid + 2];

    const float rx[4][3] = {
        {qa.x, qa.y, qa.z},
        {qa.w, qb.x, qb.y},
        {qb.z, qb.w, qc.x},
        {qc.y, qc.z, qc.w},
    };

    float res[4][3];
#pragma unroll
    for (int i = 0; i < 4; ++i) {
        const float x0 = rx[i][0];
        const float x1 = rx[i][1];
        const float an = rx[i][2];
        const float s = __sinf(an);
        const float c = __cosf(an);

        float h[4];
#pragma unroll
        for (int r = 0; r < 4; ++r) {
            float acc = wb[r];
            acc = fmaf(c,  w[r][4], acc);
            acc = fmaf(s,  w[r][3], acc);
            acc = fmaf(an, w[r][2], acc);
            acc = fmaf(x1, w[r][1], acc);
            acc = fmaf(x0, w[r][0], acc);
            h[r] = acc;
        }

        res[i][0] = h[0];
        res[i][1] = h[1];
        res[i][2] = fast_atan2f(h[2] * (1.0f + fabsf(h[3])),
                                h[3] * (1.0f + fabsf(h[2])));
    }

    sbuf[3 * tid + 0] = make_float4(res[0][0], res[0][1], res[0][2], res[1][0]);
    sbuf[3 * tid + 1] = make_float4(res[1][1], res[1][2], res[2][0], res[2][1]);
    sbuf[3 * tid + 2] = make_float4(res[2][2], res[3][0], res[3][1], res[3][2]);
    __syncthreads();

    // Phase 3: perfectly coalesced LDS -> global (plain stores).
#pragma unroll
    for (int k = 0; k < 3; ++k) {
        const int idx = k * 256 + tid;
        if (EXACT || base + idx < nf4) o4[base + idx] = sbuf[idx];
    }
}

// Tail: rows not covered by the 4-row vector path (B % 4 != 0).
__global__ void net_tail_kernel(
    const float* __restrict__ x,
    const float* __restrict__ W,
    const float* __restrict__ bias,
    float*       __restrict__ out,
    int row0, int nrows)
{
    const int i = blockIdx.x * blockDim.x + threadIdx.x;
    if (i >= nrows) return;
    const int row = row0 + i;

    const float x0 = x[row * 3 + 0];
    const float x1 = x[row * 3 + 1];
    const float an = x[row * 3 + 2];
    const float s = __sinf(an);
    const float c = __cosf(an);

    float h[4];
#pragma unroll
    for (int r = 0; r < 4; ++r) {
        float acc = W[r * 6 + 5] + bias[r];
        acc = fmaf(c,  W[r * 6 + 4], acc);
        acc = fmaf(s,  W[r * 6 + 3], acc);
        acc = fmaf(an, W[r * 6 + 2], acc);
        acc = fmaf(x1, W[r * 6 + 1], acc);
        acc = fmaf(x0, W[r * 6 + 0], acc);
        h[r] = acc;
    }
    out[row * 3 + 0] = h[0];
    out[row * 3 + 1] = h[1];
    out[row * 3 + 2] = fast_atan2f(h[2] * (1.0f + fabsf(h[3])),
                                   h[3] * (1.0f + fabsf(h[2])));
}

extern "C" void kernel_launch(void* const* d_in, const int* in_sizes, int n_in,
                              void* d_out, int out_size, void* d_ws, size_t ws_size,
                              hipStream_t stream) {
    const float* x    = (const float*)d_in[0];
    const float* W    = (const float*)d_in[1];
    const float* bias = (const float*)d_in[2];
    float* out        = (float*)d_out;

    const int B = in_sizes[0] / 3;          // number of rows
    const int nquad = B / 4;                // 4-row groups
    const int tail_rows = B - nquad * 4;
    const int nf4 = nquad * 3;              // total float4s in vector path

    if (nquad > 0) {
        const int block = 256;
        const int grid = (nquad + block - 1) / block;   // 256 quads per block
        if (nf4 % 768 == 0) {
            // Exact shape (benched case: 8192 * 768): zero bounds checks.
            net_main_kernel<true><<<grid, block, 0, stream>>>(
                (const float4*)x, W, bias, (float4*)out, nf4);
        } else {
            net_main_kernel<false><<<grid, block, 0, stream>>>(
                (const float4*)x, W, bias, (float4*)out, nf4);
        }
    }
    if (tail_rows > 0) {
        net_tail_kernel<<<1, 64, 0, stream>>>(x, W, bias, out, nquad * 4, tail_rows);
    }
}